// Round 1
// baseline (129.052 us; speedup 1.0000x reference)
//
#include <hip/hip_runtime.h>

typedef __attribute__((ext_vector_type(8))) short bf16x8;
typedef __attribute__((ext_vector_type(4))) float f32x4;

__device__ inline unsigned short f2bf(float f) {
  union { float f; unsigned u; } v; v.f = f;
  unsigned r = v.u + 0x7FFFu + ((v.u >> 16) & 1u);   // round-to-nearest-even
  return (unsigned short)(r >> 16);
}

// One wave (64 lanes) per row of 512 f32: normalize to unit L2 norm, emit bf16 bits.
__global__ __launch_bounds__(256) void normalize_rows_512(
    const float* __restrict__ in, unsigned short* __restrict__ out, int rows) {
  const int w = threadIdx.x >> 6, lane = threadIdx.x & 63;
  const int row = blockIdx.x * 4 + w;
  if (row >= rows) return;
  const float* p = in + (size_t)row * 512 + lane * 8;
  float4 a = *reinterpret_cast<const float4*>(p);
  float4 b = *reinterpret_cast<const float4*>(p + 4);
  float ss = a.x*a.x + a.y*a.y + a.z*a.z + a.w*a.w
           + b.x*b.x + b.y*b.y + b.z*b.z + b.w*b.w;
  #pragma unroll
  for (int off = 32; off; off >>= 1) ss += __shfl_xor(ss, off);
  const float inv = 1.0f / fmaxf(sqrtf(ss), 1e-12f);
  unsigned short o[8];
  o[0]=f2bf(a.x*inv); o[1]=f2bf(a.y*inv); o[2]=f2bf(a.z*inv); o[3]=f2bf(a.w*inv);
  o[4]=f2bf(b.x*inv); o[5]=f2bf(b.y*inv); o[6]=f2bf(b.z*inv); o[7]=f2bf(b.w*inv);
  *reinterpret_cast<uint4*>(out + (size_t)row * 512 + lane * 8) =
      *reinterpret_cast<uint4*>(o);
}

// C[8192,4096] logits = (1+2l)*(Xn . WnT) - 2l, bf16 MFMA, 128x128 tile, BK=32.
#define BM 128
#define BN 128
#define BK 32
#define LDK 40  // padded row stride in bf16 elems (80 B: 16B-aligned, ~2-way banks)

__global__ __launch_bounds__(256) void gemm_logits(
    const unsigned short* __restrict__ Xb, const unsigned short* __restrict__ Wb,
    const float* __restrict__ lambd, float* __restrict__ out) {
  __shared__ unsigned short Xs[BM * LDK];
  __shared__ unsigned short Ws[BN * LDK];
  const int tid  = threadIdx.x;
  const int lane = tid & 63;
  const int wid  = tid >> 6;           // 0..3
  const int wm = wid >> 1, wn = wid & 1;  // 2x2 wave grid, 64x64 per wave
  const int lrow = lane & 15, kg = lane >> 4;
  const int bm0 = blockIdx.y * BM;
  const int bn0 = blockIdx.x * BN;

  f32x4 acc[4][4];
  #pragma unroll
  for (int m = 0; m < 4; ++m)
    #pragma unroll
    for (int n = 0; n < 4; ++n) { f32x4 z = {0.f,0.f,0.f,0.f}; acc[m][n] = z; }

  const int sr = tid >> 2;             // 0..63
  const int sc = (tid & 3) << 3;       // 0,8,16,24

  for (int ko = 0; ko < 512; ko += BK) {
    #pragma unroll
    for (int p = 0; p < 2; ++p) {
      const int r = p * 64 + sr;
      *reinterpret_cast<uint4*>(&Xs[r * LDK + sc]) =
          *reinterpret_cast<const uint4*>(&Xb[(size_t)(bm0 + r) * 512 + ko + sc]);
      *reinterpret_cast<uint4*>(&Ws[r * LDK + sc]) =
          *reinterpret_cast<const uint4*>(&Wb[(size_t)(bn0 + r) * 512 + ko + sc]);
    }
    __syncthreads();
    bf16x8 af[4], bfr[4];
    #pragma unroll
    for (int m = 0; m < 4; ++m)
      af[m] = *reinterpret_cast<const bf16x8*>(&Xs[(wm*64 + m*16 + lrow) * LDK + kg*8]);
    #pragma unroll
    for (int n = 0; n < 4; ++n)
      bfr[n] = *reinterpret_cast<const bf16x8*>(&Ws[(wn*64 + n*16 + lrow) * LDK + kg*8]);
    #pragma unroll
    for (int m = 0; m < 4; ++m)
      #pragma unroll
      for (int n = 0; n < 4; ++n)
        acc[m][n] = __builtin_amdgcn_mfma_f32_16x16x32_bf16(af[m], bfr[n], acc[m][n], 0, 0, 0);
    __syncthreads();
  }

  const float lam = lambd[0];
  const float sa = 1.0f + 2.0f * lam, sb = 2.0f * lam;
  #pragma unroll
  for (int m = 0; m < 4; ++m) {
    #pragma unroll
    for (int n = 0; n < 4; ++n) {
      const int gc = bn0 + wn*64 + n*16 + lrow;
      #pragma unroll
      for (int r = 0; r < 4; ++r) {
        const int gr = bm0 + wm*64 + m*16 + kg*4 + r;   // C/D: col=lane&15, row=(lane>>4)*4+r
        out[(size_t)gr * 4096 + gc] = sa * acc[m][n][r] - sb;
      }
    }
  }
}

// In-place sparsemax over rows of 4096 f32 = exact simplex projection (Michelot).
__global__ __launch_bounds__(256) void sparsemax_kernel(float* __restrict__ out) {
  const int tid = threadIdx.x;
  float* z = out + (size_t)blockIdx.x * 4096;
  float v[16];
  #pragma unroll
  for (int c = 0; c < 4; ++c) {
    float4 t = *reinterpret_cast<const float4*>(&z[(c * 256 + tid) * 4]);
    v[c*4+0] = t.x; v[c*4+1] = t.y; v[c*4+2] = t.z; v[c*4+3] = t.w;
  }
  __shared__ float sred[4];
  __shared__ int   cred[4];
  const int lane = tid & 63, w = tid >> 6;

  float ls = 0.f;
  #pragma unroll
  for (int j = 0; j < 16; ++j) ls += v[j];
  #pragma unroll
  for (int off = 32; off; off >>= 1) ls += __shfl_xor(ls, off);
  if (lane == 0) sred[w] = ls;
  __syncthreads();
  float tau = (sred[0] + sred[1] + sred[2] + sred[3] - 1.0f) * (1.0f / 4096.0f);
  int prevC = 4096;

  for (int it = 0; it < 32; ++it) {
    __syncthreads();   // protect sred/cred reuse
    float s = 0.f; int c = 0;
    #pragma unroll
    for (int j = 0; j < 16; ++j) { if (v[j] > tau) { s += v[j]; ++c; } }
    #pragma unroll
    for (int off = 32; off; off >>= 1) { s += __shfl_xor(s, off); c += __shfl_xor(c, off); }
    if (lane == 0) { sred[w] = s; cred[w] = c; }
    __syncthreads();
    const float S = sred[0] + sred[1] + sred[2] + sred[3];
    const int   C = cred[0] + cred[1] + cred[2] + cred[3];
    tau = (S - 1.0f) / (float)C;      // supports are nested: equal count => converged
    if (C == prevC) break;
    prevC = C;
  }

  #pragma unroll
  for (int c4 = 0; c4 < 4; ++c4) {
    float4 t;
    t.x = fmaxf(v[c4*4+0] - tau, 0.f);
    t.y = fmaxf(v[c4*4+1] - tau, 0.f);
    t.z = fmaxf(v[c4*4+2] - tau, 0.f);
    t.w = fmaxf(v[c4*4+3] - tau, 0.f);
    *reinterpret_cast<float4*>(&z[(c4 * 256 + tid) * 4]) = t;
  }
}

extern "C" void kernel_launch(void* const* d_in, const int* in_sizes, int n_in,
                              void* d_out, int out_size, void* d_ws, size_t ws_size,
                              hipStream_t stream) {
  const float* x     = (const float*)d_in[0];   // [8192, 512]
  const float* wgt   = (const float*)d_in[1];   // [4096, 512]
  const float* lambd = (const float*)d_in[2];   // [1]
  float* out = (float*)d_out;                   // [8192, 4096]

  unsigned short* xb = (unsigned short*)d_ws;           // 8192*512 bf16
  unsigned short* wb = xb + (size_t)8192 * 512;         // 4096*512 bf16

  normalize_rows_512<<<8192 / 4, 256, 0, stream>>>(x, xb, 8192);
  normalize_rows_512<<<4096 / 4, 256, 0, stream>>>(wgt, wb, 4096);

  dim3 grid(4096 / BN, 8192 / BM);
  gemm_logits<<<grid, 256, 0, stream>>>(xb, wb, lambd, out);

  sparsemax_kernel<<<8192, 256, 0, stream>>>(out);
}